// Round 1
// baseline (248.618 us; speedup 1.0000x reference)
//
#include <hip/hip_runtime.h>

// SensoryModule: out[b, 0:M]   = relu(velocities*gamma_dynamic*w_Ia + b_Ia)
//                out[b, M:2M]  = relu((lengths+gamma_static)*w_II + b_II)
//                out[b, 2M:3M] = relu(forces*w_Ib + b_Ib)
// B=16384, M=512. Pure elementwise, memory-bound. float4 vectorized.

#define BB 16384
#define MM 512
#define M4 (MM / 4)          // 128 float4 groups per row
#define OUT_ROW (3 * MM)     // 1536 floats per output row

__global__ __launch_bounds__(256) void sensory_kernel(
    const float4* __restrict__ lengths,
    const float4* __restrict__ velocities,
    const float4* __restrict__ forces,
    const float4* __restrict__ gamma_static,
    const float4* __restrict__ gamma_dynamic,
    const float* __restrict__ w_Ia, const float* __restrict__ b_Ia,
    const float* __restrict__ w_II, const float* __restrict__ b_II,
    const float* __restrict__ w_Ib, const float* __restrict__ b_Ib,
    float* __restrict__ out)
{
    const long total = (long)BB * M4;                 // 2,097,152 float4 work items
    const long stride = (long)gridDim.x * blockDim.x;
    for (long i = (long)blockIdx.x * blockDim.x + threadIdx.x; i < total; i += stride) {
        const int b  = (int)(i >> 7);                 // i / 128
        const int m4 = (int)(i & 127);                // i % 128
        const int m  = m4 << 2;

        // big-array loads: fully coalesced float4
        const float4 v  = velocities[i];
        const float4 gd = gamma_dynamic[i];
        const float4 l  = lengths[i];
        const float4 gs = gamma_static[i];
        const float4 f  = forces[i];

        // per-muscle weights: 2 KB each, cache-resident broadcast
        const float4 wIa = *(const float4*)(w_Ia + m);
        const float4 bIa = *(const float4*)(b_Ia + m);
        const float4 wII = *(const float4*)(w_II + m);
        const float4 bII = *(const float4*)(b_II + m);
        const float4 wIb = *(const float4*)(w_Ib + m);
        const float4 bIb = *(const float4*)(b_Ib + m);

        float4 ia, ii, ib;
        ia.x = fmaxf(fmaf(v.x * gd.x, wIa.x, bIa.x), 0.f);
        ia.y = fmaxf(fmaf(v.y * gd.y, wIa.y, bIa.y), 0.f);
        ia.z = fmaxf(fmaf(v.z * gd.z, wIa.z, bIa.z), 0.f);
        ia.w = fmaxf(fmaf(v.w * gd.w, wIa.w, bIa.w), 0.f);

        ii.x = fmaxf(fmaf(l.x + gs.x, wII.x, bII.x), 0.f);
        ii.y = fmaxf(fmaf(l.y + gs.y, wII.y, bII.y), 0.f);
        ii.z = fmaxf(fmaf(l.z + gs.z, wII.z, bII.z), 0.f);
        ii.w = fmaxf(fmaf(l.w + gs.w, wII.w, bII.w), 0.f);

        ib.x = fmaxf(fmaf(f.x, wIb.x, bIb.x), 0.f);
        ib.y = fmaxf(fmaf(f.y, wIb.y, bIb.y), 0.f);
        ib.z = fmaxf(fmaf(f.z, wIb.z, bIb.z), 0.f);
        ib.w = fmaxf(fmaf(f.w, wIb.w, bIb.w), 0.f);

        // output row b: [Ia | II | Ib], each MM floats
        float4* orow = (float4*)(out + (long)b * OUT_ROW);
        orow[m4]           = ia;   // offset 0
        orow[m4 + M4]      = ii;   // offset MM floats
        orow[m4 + 2 * M4]  = ib;   // offset 2*MM floats
    }
}

extern "C" void kernel_launch(void* const* d_in, const int* in_sizes, int n_in,
                              void* d_out, int out_size, void* d_ws, size_t ws_size,
                              hipStream_t stream) {
    const float4* lengths       = (const float4*)d_in[0];
    const float4* velocities    = (const float4*)d_in[1];
    const float4* forces        = (const float4*)d_in[2];
    const float4* gamma_static  = (const float4*)d_in[3];
    const float4* gamma_dynamic = (const float4*)d_in[4];
    const float*  w_Ia = (const float*)d_in[5];
    const float*  b_Ia = (const float*)d_in[6];
    const float*  w_II = (const float*)d_in[7];
    const float*  b_II = (const float*)d_in[8];
    const float*  w_Ib = (const float*)d_in[9];
    const float*  b_Ib = (const float*)d_in[10];
    float* out = (float*)d_out;

    const long total = (long)BB * M4;               // 2,097,152
    int block = 256;
    int grid = (int)((total + block - 1) / block);  // 8192
    if (grid > 2048) grid = 2048;                   // grid-stride the rest (G11)

    sensory_kernel<<<grid, block, 0, stream>>>(
        lengths, velocities, forces, gamma_static, gamma_dynamic,
        w_Ia, b_Ia, w_II, b_II, w_Ib, b_Ib, out);
}

// Round 2
// 243.501 us; speedup vs baseline: 1.0210x; 1.0210x over previous
//
#include <hip/hip_runtime.h>

// SensoryModule: out[b, 0:M]   = relu(velocities*gamma_dynamic*w_Ia + b_Ia)
//                out[b, M:2M]  = relu((lengths+gamma_static)*w_II + b_II)
//                out[b, 2M:3M] = relu(forces*w_Ib + b_Ib)
// B=16384, M=512. Pure elementwise, memory-bound.
//
// Round-2 structure: each thread owns a FIXED m4 (weight fragments hoisted
// to registers, loaded once) and iterates over 4 rows (b0, b0+4096, ...).
// Full unroll -> ~20 independent float4 loads in flight per wave (MLP).
// Nontemporal stores: out is write-once, keep it out of L2/L3 so the
// input arrays stay cache-resident (harness restore leaves them in L3).

#define BB 16384
#define MM 512
#define M4 (MM / 4)          // 128 float4 groups per row
#define OUT_ROW (3 * MM)     // 1536 floats per output row
#define ROWS_PER_THREAD 4
#define ROW_STRIDE 4096      // BB / ROWS_PER_THREAD

__device__ __forceinline__ void nt_store4(float4* p, float4 v) {
    __builtin_nontemporal_store(v.x, &p->x);
    __builtin_nontemporal_store(v.y, &p->y);
    __builtin_nontemporal_store(v.z, &p->z);
    __builtin_nontemporal_store(v.w, &p->w);
}

__global__ __launch_bounds__(256) void sensory_kernel(
    const float4* __restrict__ lengths,
    const float4* __restrict__ velocities,
    const float4* __restrict__ forces,
    const float4* __restrict__ gamma_static,
    const float4* __restrict__ gamma_dynamic,
    const float* __restrict__ w_Ia, const float* __restrict__ b_Ia,
    const float* __restrict__ w_II, const float* __restrict__ b_II,
    const float* __restrict__ w_Ib, const float* __restrict__ b_Ib,
    float* __restrict__ out)
{
    const int t  = blockIdx.x * 256 + threadIdx.x;   // 0 .. 524287
    const int m4 = t & (M4 - 1);                     // fixed per thread
    const int b0 = t >> 7;                           // 0 .. 4095
    const int m  = m4 << 2;

    // per-muscle weights: loaded ONCE per thread, broadcast from L1/L2
    const float4 wIa = *(const float4*)(w_Ia + m);
    const float4 bIa = *(const float4*)(b_Ia + m);
    const float4 wII = *(const float4*)(w_II + m);
    const float4 bII = *(const float4*)(b_II + m);
    const float4 wIb = *(const float4*)(w_Ib + m);
    const float4 bIb = *(const float4*)(b_Ib + m);

    // issue ALL big loads first (independent -> deep MLP), then compute+store
    float4 v[ROWS_PER_THREAD], gd[ROWS_PER_THREAD], l[ROWS_PER_THREAD],
           gs[ROWS_PER_THREAD], f[ROWS_PER_THREAD];

#pragma unroll
    for (int r = 0; r < ROWS_PER_THREAD; ++r) {
        const long i = (long)(b0 + r * ROW_STRIDE) * M4 + m4;
        v[r]  = velocities[i];
        gd[r] = gamma_dynamic[i];
        l[r]  = lengths[i];
        gs[r] = gamma_static[i];
        f[r]  = forces[i];
    }

#pragma unroll
    for (int r = 0; r < ROWS_PER_THREAD; ++r) {
        float4 ia, ii, ib;
        ia.x = fmaxf(fmaf(v[r].x * gd[r].x, wIa.x, bIa.x), 0.f);
        ia.y = fmaxf(fmaf(v[r].y * gd[r].y, wIa.y, bIa.y), 0.f);
        ia.z = fmaxf(fmaf(v[r].z * gd[r].z, wIa.z, bIa.z), 0.f);
        ia.w = fmaxf(fmaf(v[r].w * gd[r].w, wIa.w, bIa.w), 0.f);

        ii.x = fmaxf(fmaf(l[r].x + gs[r].x, wII.x, bII.x), 0.f);
        ii.y = fmaxf(fmaf(l[r].y + gs[r].y, wII.y, bII.y), 0.f);
        ii.z = fmaxf(fmaf(l[r].z + gs[r].z, wII.z, bII.z), 0.f);
        ii.w = fmaxf(fmaf(l[r].w + gs[r].w, wII.w, bII.w), 0.f);

        ib.x = fmaxf(fmaf(f[r].x, wIb.x, bIb.x), 0.f);
        ib.y = fmaxf(fmaf(f[r].y, wIb.y, bIb.y), 0.f);
        ib.z = fmaxf(fmaf(f[r].z, wIb.z, bIb.z), 0.f);
        ib.w = fmaxf(fmaf(f[r].w, wIb.w, bIb.w), 0.f);

        float4* orow = (float4*)(out + (long)(b0 + r * ROW_STRIDE) * OUT_ROW);
        nt_store4(&orow[m4],          ia);
        nt_store4(&orow[m4 + M4],     ii);
        nt_store4(&orow[m4 + 2 * M4], ib);
    }
}

extern "C" void kernel_launch(void* const* d_in, const int* in_sizes, int n_in,
                              void* d_out, int out_size, void* d_ws, size_t ws_size,
                              hipStream_t stream) {
    const float4* lengths       = (const float4*)d_in[0];
    const float4* velocities    = (const float4*)d_in[1];
    const float4* forces       = (const float4*)d_in[2];
    const float4* gamma_static  = (const float4*)d_in[3];
    const float4* gamma_dynamic = (const float4*)d_in[4];
    const float*  w_Ia = (const float*)d_in[5];
    const float*  b_Ia = (const float*)d_in[6];
    const float*  w_II = (const float*)d_in[7];
    const float*  b_II = (const float*)d_in[8];
    const float*  w_Ib = (const float*)d_in[9];
    const float*  b_Ib = (const float*)d_in[10];
    float* out = (float*)d_out;

    // exactly one thread per (b0, m4): 4096 * 128 = 524288 threads = 2048 blocks
    const int block = 256;
    const int grid  = (BB / ROWS_PER_THREAD) * M4 / block;   // 2048

    sensory_kernel<<<grid, block, 0, stream>>>(
        lengths, velocities, forces, gamma_static, gamma_dynamic,
        w_Ia, b_Ia, w_II, b_II, w_Ib, b_Ib, out);
}

// Round 3
// 241.537 us; speedup vs baseline: 1.0293x; 1.0081x over previous
//
#include <hip/hip_runtime.h>

// SensoryModule: out[b, 0:M]   = relu(velocities*gamma_dynamic*w_Ia + b_Ia)
//                out[b, M:2M]  = relu((lengths+gamma_static)*w_II + b_II)
//                out[b, 2M:3M] = relu(forces*w_Ib + b_Ib)
// B=16384, M=512. Pure elementwise, memory-bound.
//
// Round-3: one float4-triple per thread (2,097,152 threads, 8192 blocks).
//  - ext_vector float4 so __builtin_nontemporal_store emits ONE
//    global_store_dwordx4 nt per output fragment (round-2 bug: HIP float4
//    is a struct -> 4 scalar nt stores, stride-16B fragmentation).
//  - 8192 blocks = 32 blocks/CU sequentially -> wave replacement keeps
//    loads issuing while old blocks drain stores (round-2 had exactly one
//    generation: store-drain tail had zero load overlap).
//  - nt stores keep the write-once output from evicting L3-resident inputs.

#define BB 16384
#define MM 512
#define M4 (MM / 4)          // 128 float4 groups per row
#define OUT_ROW4 (3 * M4)    // 384 float4 per output row

typedef float f4 __attribute__((ext_vector_type(4)));

__global__ __launch_bounds__(256) void sensory_kernel(
    const f4* __restrict__ lengths,
    const f4* __restrict__ velocities,
    const f4* __restrict__ forces,
    const f4* __restrict__ gamma_static,
    const f4* __restrict__ gamma_dynamic,
    const f4* __restrict__ w_Ia4, const f4* __restrict__ b_Ia4,
    const f4* __restrict__ w_II4, const f4* __restrict__ b_II4,
    const f4* __restrict__ w_Ib4, const f4* __restrict__ b_Ib4,
    f4* __restrict__ out)
{
    const int t  = blockIdx.x * 256 + threadIdx.x;   // 0 .. 2097151 == flat [B,M4] index
    const int m4 = t & (M4 - 1);
    const int b  = t >> 7;

    // big-array loads: flat index IS t (fully coalesced, 1 KB/wave/instr)
    const f4 v  = velocities[t];
    const f4 gd = gamma_dynamic[t];
    const f4 l  = lengths[t];
    const f4 gs = gamma_static[t];
    const f4 f  = forces[t];

    // per-muscle weights: 2 KB each -> L1-resident after first touch per CU
    const f4 wIa = w_Ia4[m4];
    const f4 bIa = b_Ia4[m4];
    const f4 wII = w_II4[m4];
    const f4 bII = b_II4[m4];
    const f4 wIb = w_Ib4[m4];
    const f4 bIb = b_Ib4[m4];

    f4 ia, ii, ib;
    ia.x = fmaxf(fmaf(v.x * gd.x, wIa.x, bIa.x), 0.f);
    ia.y = fmaxf(fmaf(v.y * gd.y, wIa.y, bIa.y), 0.f);
    ia.z = fmaxf(fmaf(v.z * gd.z, wIa.z, bIa.z), 0.f);
    ia.w = fmaxf(fmaf(v.w * gd.w, wIa.w, bIa.w), 0.f);

    ii.x = fmaxf(fmaf(l.x + gs.x, wII.x, bII.x), 0.f);
    ii.y = fmaxf(fmaf(l.y + gs.y, wII.y, bII.y), 0.f);
    ii.z = fmaxf(fmaf(l.z + gs.z, wII.z, bII.z), 0.f);
    ii.w = fmaxf(fmaf(l.w + gs.w, wII.w, bII.w), 0.f);

    ib.x = fmaxf(fmaf(f.x, wIb.x, bIb.x), 0.f);
    ib.y = fmaxf(fmaf(f.y, wIb.y, bIb.y), 0.f);
    ib.z = fmaxf(fmaf(f.z, wIb.z, bIb.z), 0.f);
    ib.w = fmaxf(fmaf(f.w, wIb.w, bIb.w), 0.f);

    // output row b: [Ia | II | Ib]; one global_store_dwordx4 nt each
    f4* orow = out + (long)b * OUT_ROW4;
    __builtin_nontemporal_store(ia, &orow[m4]);
    __builtin_nontemporal_store(ii, &orow[m4 + M4]);
    __builtin_nontemporal_store(ib, &orow[m4 + 2 * M4]);
}

extern "C" void kernel_launch(void* const* d_in, const int* in_sizes, int n_in,
                              void* d_out, int out_size, void* d_ws, size_t ws_size,
                              hipStream_t stream) {
    const f4* lengths       = (const f4*)d_in[0];
    const f4* velocities    = (const f4*)d_in[1];
    const f4* forces        = (const f4*)d_in[2];
    const f4* gamma_static  = (const f4*)d_in[3];
    const f4* gamma_dynamic = (const f4*)d_in[4];
    const f4*  w_Ia = (const f4*)d_in[5];
    const f4*  b_Ia = (const f4*)d_in[6];
    const f4*  w_II = (const f4*)d_in[7];
    const f4*  b_II = (const f4*)d_in[8];
    const f4*  w_Ib = (const f4*)d_in[9];
    const f4*  b_Ib = (const f4*)d_in[10];
    f4* out = (f4*)d_out;

    // one thread per (b, m4): 16384 * 128 = 2,097,152 threads = 8192 blocks
    const int block = 256;
    const int grid  = BB * M4 / block;   // 8192

    sensory_kernel<<<grid, block, 0, stream>>>(
        lengths, velocities, forces, gamma_static, gamma_dynamic,
        w_Ia, b_Ia, w_II, b_II, w_Ib, b_Ib, out);
}

// Round 5
// 227.789 us; speedup vs baseline: 1.0914x; 1.0604x over previous
//
#include <hip/hip_runtime.h>

// SensoryModule: out[b, 0:M]   = relu(velocities*gamma_dynamic*w_Ia + b_Ia)
//                out[b, M:2M]  = relu((lengths+gamma_static)*w_II + b_II)
//                out[b, 2M:3M] = relu(forces*w_Ib + b_Ib)
// B=16384, M=512. Pure elementwise, memory-bound.
//
// Round-4 (resubmit; round-4 bench never ran - GPU acquisition timeout).
// Deep per-wave MLP:
//  - 2048 blocks x 256 thr, 4 f4-triples per thread, iteration stride
//    524288 f4 (== 0 mod 128) so m4 is thread-invariant -> weights hoisted.
//  - ALL 20 big loads issued before any compute; sched_barrier(0) after the
//    load cluster prevents the compiler re-rolling (round-2: VGPR=36 proved
//    it serialized into 5-load groups -> only ~5KB in flight per wave).
//  - nontemporal loads: read-once streams, don't allocate in L3 on miss ->
//    stops self-eviction of not-yet-read input lines (FETCH was 49% miss).
//  - nontemporal dwordx4 stores (kept from round-3).

#define BB 16384
#define MM 512
#define M4 (MM / 4)            // 128 f4 per input row
#define OUT_ROW4 (3 * M4)      // 384 f4 per output row
#define NBLOCK 2048
#define NTHREADS (NBLOCK * 256)   // 524288
#define ITERS 4                   // NTHREADS * ITERS == BB*M4

typedef float f4 __attribute__((ext_vector_type(4)));

__global__ __launch_bounds__(256) void sensory_kernel(
    const f4* __restrict__ lengths,
    const f4* __restrict__ velocities,
    const f4* __restrict__ forces,
    const f4* __restrict__ gamma_static,
    const f4* __restrict__ gamma_dynamic,
    const f4* __restrict__ w_Ia4, const f4* __restrict__ b_Ia4,
    const f4* __restrict__ w_II4, const f4* __restrict__ b_II4,
    const f4* __restrict__ w_Ib4, const f4* __restrict__ b_Ib4,
    f4* __restrict__ out)
{
    const int t  = blockIdx.x * 256 + threadIdx.x;   // 0 .. 524287
    const int m4 = t & (M4 - 1);                     // invariant across iters

    // per-muscle weights: loaded once, L1/L2-resident broadcast
    const f4 wIa = w_Ia4[m4];
    const f4 bIa = b_Ia4[m4];
    const f4 wII = w_II4[m4];
    const f4 bII = b_II4[m4];
    const f4 wIb = w_Ib4[m4];
    const f4 bIb = b_Ib4[m4];

    // ---- issue ALL big loads (20 x dwordx4 nt) before any compute ----
    f4 v[ITERS], gd[ITERS], l[ITERS], gs[ITERS], f[ITERS];
#pragma unroll
    for (int r = 0; r < ITERS; ++r) {
        const int i = t + r * NTHREADS;
        v[r]  = __builtin_nontemporal_load(&velocities[i]);
        gd[r] = __builtin_nontemporal_load(&gamma_dynamic[i]);
        l[r]  = __builtin_nontemporal_load(&lengths[i]);
        gs[r] = __builtin_nontemporal_load(&gamma_static[i]);
        f[r]  = __builtin_nontemporal_load(&forces[i]);
    }
    // hard scheduling fence: nothing may cross -> loads stay clustered,
    // ~20KB in flight per wave
    __builtin_amdgcn_sched_barrier(0);

#pragma unroll
    for (int r = 0; r < ITERS; ++r) {
        const int i = t + r * NTHREADS;
        const int b = i >> 7;                        // row index

        f4 ia, ii, ib;
        ia.x = fmaxf(fmaf(v[r].x * gd[r].x, wIa.x, bIa.x), 0.f);
        ia.y = fmaxf(fmaf(v[r].y * gd[r].y, wIa.y, bIa.y), 0.f);
        ia.z = fmaxf(fmaf(v[r].z * gd[r].z, wIa.z, bIa.z), 0.f);
        ia.w = fmaxf(fmaf(v[r].w * gd[r].w, wIa.w, bIa.w), 0.f);

        ii.x = fmaxf(fmaf(l[r].x + gs[r].x, wII.x, bII.x), 0.f);
        ii.y = fmaxf(fmaf(l[r].y + gs[r].y, wII.y, bII.y), 0.f);
        ii.z = fmaxf(fmaf(l[r].z + gs[r].z, wII.z, bII.z), 0.f);
        ii.w = fmaxf(fmaf(l[r].w + gs[r].w, wII.w, bII.w), 0.f);

        ib.x = fmaxf(fmaf(f[r].x, wIb.x, bIb.x), 0.f);
        ib.y = fmaxf(fmaf(f[r].y, wIb.y, bIb.y), 0.f);
        ib.z = fmaxf(fmaf(f[r].z, wIb.z, bIb.z), 0.f);
        ib.w = fmaxf(fmaf(f[r].w, wIb.w, bIb.w), 0.f);

        f4* orow = out + (long)b * OUT_ROW4;
        __builtin_nontemporal_store(ia, &orow[m4]);
        __builtin_nontemporal_store(ii, &orow[m4 + M4]);
        __builtin_nontemporal_store(ib, &orow[m4 + 2 * M4]);
    }
}

extern "C" void kernel_launch(void* const* d_in, const int* in_sizes, int n_in,
                              void* d_out, int out_size, void* d_ws, size_t ws_size,
                              hipStream_t stream) {
    const f4* lengths       = (const f4*)d_in[0];
    const f4* velocities    = (const f4*)d_in[1];
    const f4* forces        = (const f4*)d_in[2];
    const f4* gamma_static  = (const f4*)d_in[3];
    const f4* gamma_dynamic = (const f4*)d_in[4];
    const f4*  w_Ia = (const f4*)d_in[5];
    const f4*  b_Ia = (const f4*)d_in[6];
    const f4*  w_II = (const f4*)d_in[7];
    const f4*  b_II = (const f4*)d_in[8];
    const f4*  w_Ib = (const f4*)d_in[9];
    const f4*  b_Ib = (const f4*)d_in[10];
    f4* out = (f4*)d_out;

    sensory_kernel<<<NBLOCK, 256, 0, stream>>>(
        lengths, velocities, forces, gamma_static, gamma_dynamic,
        w_Ia, b_Ia, w_II, b_II, w_Ib, b_Ib, out);
}

// Round 6
// 226.902 us; speedup vs baseline: 1.0957x; 1.0039x over previous
//
#include <hip/hip_runtime.h>

// SensoryModule: out[b, 0:M]   = relu(velocities*gamma_dynamic*w_Ia + b_Ia)
//                out[b, M:2M]  = relu((lengths+gamma_static)*w_II + b_II)
//                out[b, 2M:3M] = relu(forces*w_Ib + b_Ib)
// B=16384, M=512. Pure elementwise, memory-bound.
//
// Round-6: depth-4 software pipeline (vs round-4's burst-then-drain).
//  - 1024 blocks x 256 thr, 8 f4-triples per thread, stride 262144 f4
//    (== 0 mod 128) so m4 is thread-invariant -> weights hoisted.
//  - 4 named register buffer groups A-D (compile-time indexing, no scratch).
//    Prologue fills A-D (20 nt loads in flight); steady state: compute+store
//    group X, immediately re-issue its 5 loads for iter r+4. Loads stay
//    ~15-20 deep CONTINUOUSLY and stores interleave with load issue ->
//    sustained mixed streams, no per-wave drain phase.
//  - nt loads (no L3 allocate on read-once streams), nt dwordx4 stores.

#define BB 16384
#define MM 512
#define M4 (MM / 4)              // 128 f4 per input row
#define OUT_ROW4 (3 * M4)        // 384 f4 per output row
#define NBLOCK 1024
#define NTHREADS (NBLOCK * 256)  // 262144
#define ITERS 8                  // NTHREADS * ITERS == BB*M4 == 2097152

typedef float f4 __attribute__((ext_vector_type(4)));

__global__ __launch_bounds__(256) void sensory_kernel(
    const f4* __restrict__ lengths,
    const f4* __restrict__ velocities,
    const f4* __restrict__ forces,
    const f4* __restrict__ gamma_static,
    const f4* __restrict__ gamma_dynamic,
    const f4* __restrict__ w_Ia4, const f4* __restrict__ b_Ia4,
    const f4* __restrict__ w_II4, const f4* __restrict__ b_II4,
    const f4* __restrict__ w_Ib4, const f4* __restrict__ b_Ib4,
    f4* __restrict__ out)
{
    const int t  = blockIdx.x * 256 + threadIdx.x;   // 0 .. 262143
    const int m4 = t & (M4 - 1);                     // invariant across iters

    // per-muscle weights: loaded once, cache-resident broadcast
    const f4 wIa = w_Ia4[m4];
    const f4 bIa = b_Ia4[m4];
    const f4 wII = w_II4[m4];
    const f4 bII = b_II4[m4];
    const f4 wIb = w_Ib4[m4];
    const f4 bIb = b_Ib4[m4];

    f4 vA, gdA, lA, gsA, fA;
    f4 vB, gdB, lB, gsB, fB;
    f4 vC, gdC, lC, gsC, fC;
    f4 vD, gdD, lD, gsD, fD;

#define LOADG(S, r) do {                                             \
        const int i_ = t + (r) * NTHREADS;                           \
        v##S  = __builtin_nontemporal_load(&velocities[i_]);         \
        gd##S = __builtin_nontemporal_load(&gamma_dynamic[i_]);      \
        l##S  = __builtin_nontemporal_load(&lengths[i_]);            \
        gs##S = __builtin_nontemporal_load(&gamma_static[i_]);       \
        f##S  = __builtin_nontemporal_load(&forces[i_]);             \
    } while (0)

#define COMP(S, r) do {                                                      \
        const int i_ = t + (r) * NTHREADS;                                   \
        const int b_ = i_ >> 7;                                              \
        f4 ia, ii, ib;                                                       \
        ia.x = fmaxf(fmaf(v##S.x * gd##S.x, wIa.x, bIa.x), 0.f);             \
        ia.y = fmaxf(fmaf(v##S.y * gd##S.y, wIa.y, bIa.y), 0.f);             \
        ia.z = fmaxf(fmaf(v##S.z * gd##S.z, wIa.z, bIa.z), 0.f);             \
        ia.w = fmaxf(fmaf(v##S.w * gd##S.w, wIa.w, bIa.w), 0.f);             \
        ii.x = fmaxf(fmaf(l##S.x + gs##S.x, wII.x, bII.x), 0.f);             \
        ii.y = fmaxf(fmaf(l##S.y + gs##S.y, wII.y, bII.y), 0.f);             \
        ii.z = fmaxf(fmaf(l##S.z + gs##S.z, wII.z, bII.z), 0.f);             \
        ii.w = fmaxf(fmaf(l##S.w + gs##S.w, wII.w, bII.w), 0.f);             \
        ib.x = fmaxf(fmaf(f##S.x, wIb.x, bIb.x), 0.f);                       \
        ib.y = fmaxf(fmaf(f##S.y, wIb.y, bIb.y), 0.f);                       \
        ib.z = fmaxf(fmaf(f##S.z, wIb.z, bIb.z), 0.f);                       \
        ib.w = fmaxf(fmaf(f##S.w, wIb.w, bIb.w), 0.f);                       \
        f4* orow_ = out + (long)b_ * OUT_ROW4;                               \
        __builtin_nontemporal_store(ia, &orow_[m4]);                         \
        __builtin_nontemporal_store(ii, &orow_[m4 + M4]);                    \
        __builtin_nontemporal_store(ib, &orow_[m4 + 2 * M4]);                \
    } while (0)

    // prologue: fill all 4 buffer groups (20 loads in flight)
    LOADG(A, 0);
    LOADG(B, 1);
    LOADG(C, 2);
    LOADG(D, 3);
    __builtin_amdgcn_sched_barrier(0);   // keep the prologue burst clustered

    // steady state: consume one group, immediately refill it (depth stays ~4)
    COMP(A, 0); LOADG(A, 4);
    COMP(B, 1); LOADG(B, 5);
    COMP(C, 2); LOADG(C, 6);
    COMP(D, 3); LOADG(D, 7);

    // epilogue drain
    COMP(A, 4);
    COMP(B, 5);
    COMP(C, 6);
    COMP(D, 7);

#undef LOADG
#undef COMP
}

extern "C" void kernel_launch(void* const* d_in, const int* in_sizes, int n_in,
                              void* d_out, int out_size, void* d_ws, size_t ws_size,
                              hipStream_t stream) {
    const f4* lengths       = (const f4*)d_in[0];
    const f4* velocities    = (const f4*)d_in[1];
    const f4* forces        = (const f4*)d_in[2];
    const f4* gamma_static  = (const f4*)d_in[3];
    const f4* gamma_dynamic = (const f4*)d_in[4];
    const f4*  w_Ia = (const f4*)d_in[5];
    const f4*  b_Ia = (const f4*)d_in[6];
    const f4*  w_II = (const f4*)d_in[7];
    const f4*  b_II = (const f4*)d_in[8];
    const f4*  w_Ib = (const f4*)d_in[9];
    const f4*  b_Ib = (const f4*)d_in[10];
    f4* out = (f4*)d_out;

    sensory_kernel<<<NBLOCK, 256, 0, stream>>>(
        lengths, velocities, forces, gamma_static, gamma_dynamic,
        w_Ia, b_Ia, w_II, b_II, w_Ib, b_Ib, out);
}